// Round 11
// baseline (197.301 us; speedup 1.0000x reference)
//
#include <hip/hip_runtime.h>
#include <hip/hip_bf16.h>

// Block-local matmul: out block (b,i,j)[64x64] = A(b,i,j)[64x64] @ W(i,j)[64x64]
// B=4, M=K=N=4096, BLOCK_NUM=64.
// Round 11: PERSISTENT SEQUENTIAL-STREAM design (copy-like). 512 wgs (2/CU),
// wg = (b, i, col-half) loops 8 chunks of 64x256 sequentially along its rows:
// every wave's A/out streams advance 1KB-sequentially per chunk (64 streams
// per CU), A prefetched one chunk ahead in regs, W scalar-staged (L2/L3-hot),
// nt stores, 2 barriers/chunk.

typedef short bf16x8 __attribute__((ext_vector_type(8)));
typedef float f32x4 __attribute__((ext_vector_type(4)));

__device__ __forceinline__ unsigned short f2bf(float f) {
    union { float f; unsigned int u; } v; v.f = f;
    unsigned int u = v.u;
    u += 0x7fffu + ((u >> 16) & 1u);   // round-to-nearest-even
    return (unsigned short)(u >> 16);
}

__device__ __forceinline__ unsigned long long pack4(float4 v) {
    return  (unsigned long long)f2bf(v.x)        |
           ((unsigned long long)f2bf(v.y) << 16) |
           ((unsigned long long)f2bf(v.z) << 32) |
           ((unsigned long long)f2bf(v.w) << 48);
}

__device__ __forceinline__ unsigned long long pack4s(float a, float b,
                                                     float c, float d) {
    return  (unsigned long long)f2bf(a)        |
           ((unsigned long long)f2bf(b) << 16) |
           ((unsigned long long)f2bf(c) << 32) |
           ((unsigned long long)f2bf(d) << 48);
}

#define BELEMS 16777216ull   // 4096*4096 (batch stride, elements)

__global__ __launch_bounds__(256, 2) void block_matmul_kernel(
    const float* __restrict__ x, const float* __restrict__ w,
    float* __restrict__ out) {
    // LDS (64 KB):
    //  [0,32K)   As[m=64][k=256] bf16, 512B rows, swz byte^=((m&7)<<4)
    //  [32K,64K) Ws[n=256][c=64] bf16, 128B rows, swz byte^=((n&7)<<4)
    __shared__ char smem[65536];

    const int t   = threadIdx.x;
    const int l   = t & 63;
    const int wv  = t >> 6;
    const int lr  = l & 15;
    const int lhi = l >> 4;

    // XCD-contiguous mapping: XCD k owns i in [8k,8k+8), all b, both halves.
    int orig = blockIdx.x;            // 0..511
    int xcd  = orig & 7;
    int idx  = orig >> 3;             // 0..63
    int i = xcd * 8 + (idx >> 3);     // 0..63
    int b = (idx >> 1) & 3;           // 0..3
    int h = idx & 1;                  // 0..1

    const size_t rowbase = (size_t)i * 64;
    const size_t colbase = (size_t)h * 2048;

    const float* Ab = x + (size_t)b * BELEMS + (rowbase + wv * 16) * 4096 + colbase;
    const float* Wb = w + rowbase * 4096 + colbase;
    float*       Ob = out + (size_t)b * BELEMS + (rowbase + wv * 16) * 4096 + colbase;

    float4 areg[16];

    // A chunk: wave-private rows [wv*16,+16), one float4 inst per row = 1KB
    // contiguous; consecutive chunks advance each row stream sequentially.
#define ISSUE_A(c_) { const float* p_ = Ab + (size_t)(c_) * 256 + l * 4;      \
    _Pragma("unroll") for (int s = 0; s < 16; ++s)                            \
        areg[s] = *reinterpret_cast<const float4*>(p_ + (size_t)s * 4096); }

#define WRITE_A() { _Pragma("unroll") for (int s = 0; s < 16; ++s) {          \
        int m_ = wv * 16 + s;                                                 \
        *reinterpret_cast<unsigned long long*>(                               \
            smem + m_ * 512 + ((l * 8) ^ ((m_ & 7) << 4))) = pack4(areg[s]); } }

    // W chunk (64 contract-rows x 256 cols), scalar loads (mostly L2/L3-hot),
    // register 4x4 transpose pack -> Ws[n][c] b64 writes.
#define STAGE_W(c_) {                                                         \
    const float* p_ = Wb + (size_t)(wv * 16) * 4096 + (size_t)(c_) * 256 + l; \
    float wr_[16][4];                                                         \
    _Pragma("unroll") for (int s = 0; s < 16; ++s)                            \
        _Pragma("unroll") for (int hh = 0; hh < 4; ++hh)                      \
            wr_[s][hh] = p_[(size_t)s * 4096 + hh * 64];                      \
    _Pragma("unroll") for (int g = 0; g < 4; ++g)                             \
        _Pragma("unroll") for (int hh = 0; hh < 4; ++hh) {                    \
            int n_  = hh * 64 + l;                                            \
            int cc_ = (wv * 16 + g * 4) * 2;                                  \
            unsigned long long pk_ = pack4s(wr_[g*4+0][hh], wr_[g*4+1][hh],   \
                                            wr_[g*4+2][hh], wr_[g*4+3][hh]);  \
            *reinterpret_cast<unsigned long long*>(                           \
                smem + 32768 + n_ * 128 + (cc_ ^ ((n_ & 7) << 4))) = pk_; } }

    // ---------------- prologue: stage chunk 0 ----------------
    ISSUE_A(0);
    WRITE_A();
    STAGE_W(0);
    __syncthreads();

    // ---------------- 8 sequential chunks ----------------
    #pragma unroll 1
    for (int c = 0; c < 8; ++c) {
        if (c < 7) ISSUE_A(c + 1);    // next chunk's reads in flight all chunk

        f32x4 acc[4][4];
        #pragma unroll
        for (int a = 0; a < 4; ++a)
            #pragma unroll
            for (int z = 0; z < 4; ++z) acc[a][z] = (f32x4){0.f,0.f,0.f,0.f};

        const int m = wv * 16 + lr;
        #pragma unroll
        for (int jloc = 0; jloc < 4; ++jloc) {
            #pragma unroll
            for (int kt = 0; kt < 2; ++kt) {
                bf16x8 af = *reinterpret_cast<const bf16x8*>(
                    smem + m * 512 +
                    ((jloc * 128 + kt * 64 + lhi * 16) ^ ((m & 7) << 4)));
                #pragma unroll
                for (int nt = 0; nt < 4; ++nt) {
                    int bn = jloc * 64 + nt * 16 + lr;
                    bf16x8 bfr = *reinterpret_cast<const bf16x8*>(
                        smem + 32768 + bn * 128 +
                        ((kt * 64 + lhi * 16) ^ ((bn & 7) << 4)));
                    acc[jloc][nt] = __builtin_amdgcn_mfma_f32_16x16x32_bf16(
                        af, bfr, acc[jloc][nt], 0, 0, 0);
                }
            }
        }

        // Direct nt stores; the wave's 64 insts cover rows [wv*16,+16) x 1KB,
        // advancing sequentially with c.
        float* Op = Ob + (size_t)c * 256;
        #pragma unroll
        for (int jloc = 0; jloc < 4; ++jloc)
            #pragma unroll
            for (int nt = 0; nt < 4; ++nt)
                #pragma unroll
                for (int r = 0; r < 4; ++r)
                    __builtin_nontemporal_store(acc[jloc][nt][r],
                        Op + (size_t)(lhi * 4 + r) * 4096 +
                        jloc * 64 + nt * 16 + lr);

        __syncthreads();              // all waves done reading LDS chunk c
        if (c < 7) { WRITE_A(); STAGE_W(c + 1); }
        __syncthreads();              // LDS chunk c+1 ready
    }
}

extern "C" void kernel_launch(void* const* d_in, const int* in_sizes, int n_in,
                              void* d_out, int out_size, void* d_ws, size_t ws_size,
                              hipStream_t stream) {
    const float* x = (const float*)d_in[0];   // [4, 4096, 4096] fp32
    const float* w = (const float*)d_in[1];   // [4096, 4096] fp32
    float* out = (float*)d_out;               // [4, 4096, 4096] fp32

    dim3 grid(512);
    dim3 block(256);
    block_matmul_kernel<<<grid, block, 0, stream>>>(x, w, out);
}

// Round 14
// 115.541 us; speedup vs baseline: 1.7076x; 1.7076x over previous
//
#include <hip/hip_runtime.h>
#include <hip/hip_bf16.h>

// Block-local matmul: out block (b,i,j)[64x64] = A(b,i,j)[64x64] @ W(i,j)[64x64]
// B=4, M=K=N=4096, BLOCK_NUM=64.
// Round 14 = exact revert to Round 10 (best: 117.4us, passed).
// R12/R13 post-mortem: sc0/sc1/nt bypass stores are incoherent with the
// harness's cached zero-fill of d_out (stale-zero readback) — cache-policy
// control from instructions is a dead end on gfx950. This is the final
// kernel; 13 structural designs cluster at 117-137us = the in-situ
// mixed-stream wall (426MB HBM @ 3.6TB/s + 156MB L3-served per replay).

typedef short bf16x8 __attribute__((ext_vector_type(8)));
typedef float f32x4 __attribute__((ext_vector_type(4)));

__device__ __forceinline__ unsigned short f2bf(float f) {
    union { float f; unsigned int u; } v; v.f = f;
    unsigned int u = v.u;
    u += 0x7fffu + ((u >> 16) & 1u);   // round-to-nearest-even
    return (unsigned short)(u >> 16);
}

__device__ __forceinline__ unsigned long long pack4(float4 v) {
    return  (unsigned long long)f2bf(v.x)        |
           ((unsigned long long)f2bf(v.y) << 16) |
           ((unsigned long long)f2bf(v.z) << 32) |
           ((unsigned long long)f2bf(v.w) << 48);
}

#define BSTRIDE 16777216ull   // 4096*4096 (batch stride, elements)

// Compiler+wave-local ordering point for LDS write->read reuse.
// lgkmcnt(0) waits LDS ops only; vmcnt (global prefetches) stays untouched.
#define FENCE() asm volatile("s_waitcnt lgkmcnt(0)" ::: "memory")

__global__ __launch_bounds__(256, 3) void block_matmul_kernel(
    const float* __restrict__ x, const float* __restrict__ w,
    float* __restrict__ out) {
    // LDS map (48 KB):
    //   [0,16K)   Ws: [n=128][c=64] bf16, 128B rows, XOR-swz, SHARED (1 barrier)
    //   [16K,32K) A slots: per-wave 4KB, [16 rows][128 c] bf16, 256B rows, swz
    //   [32K,48K) bounce:  per-wave 4KB, [16 rows][64 f32], 256B rows, swz
    __shared__ char smem[49152];

    const int t  = threadIdx.x;
    const int l  = t & 63;
    const int wv = t >> 6;
    const int lr = l & 15;
    const int lk = l >> 4;

    // XCD-bijective swizzle (2048 wgs): each XCD owns a contiguous 8-i slab.
    int orig = blockIdx.x;
    int wg   = (orig & 7) * 256 + (orig >> 3);
    int i = wg >> 5;           // 0..63 row-block
    int q = wg & 31;           // 0..31 col-pair (128 cols)

    const size_t rowbase = (size_t)i * 64;
    const size_t colbase = (size_t)q * 128;

    const float* Wb    = w   + rowbase * 4096 + colbase;
    const float* Abase = x   + (rowbase + wv * 16) * 4096 + colbase;
    float*       Obase = out + (rowbase + wv * 16) * 4096 + colbase;

    char* Aslot = smem + 16384 + wv * 4096;
    char* Bslot = smem + 32768 + wv * 4096;

    // ---- W staging loads first (prologue barrier depends only on these).
    const int wn = t & 127;
    const int c0 = (t >> 7) << 2;        // 0 or 4
    float wreg[32];
    #pragma unroll
    for (int it = 0; it < 8; ++it) {
        int c = it * 8 + c0;
        #pragma unroll
        for (int r = 0; r < 4; ++r)
            wreg[it * 4 + r] = Wb[(size_t)(c + r) * 4096 + wn];
    }

    // ---- A loads: wave-private rows [wv*16, +16). Per instr: lanes cover
    // 2 consecutive rows x 512B contiguous = 8 full 128B lines.
    const int rl0 = l >> 5;              // 0..1
    const int u   = l & 31;              // float4 unit within 512B row
    const float* Alane = Abase + (size_t)rl0 * 4096 + u * 4;

#define LOADA(DST, b_) {                                                      \
    const float* Ap = Alane + (size_t)(b_) * BSTRIDE;                         \
    _Pragma("unroll") for (int s = 0; s < 8; ++s)                             \
        DST[s] = *reinterpret_cast<const float4*>(Ap + (size_t)(s * 2) * 4096); }

    float4 aA[8], aB[8];
    LOADA(aA, 0);
    LOADA(aB, 1);

    // ---- W convert + transposed swizzled write: Ws[n][c].
    #pragma unroll
    for (int it = 0; it < 8; ++it) {
        int c = it * 8 + c0;
        unsigned long long pk =
            (unsigned long long)f2bf(wreg[it * 4 + 0])         |
            ((unsigned long long)f2bf(wreg[it * 4 + 1]) << 16) |
            ((unsigned long long)f2bf(wreg[it * 4 + 2]) << 32) |
            ((unsigned long long)f2bf(wreg[it * 4 + 3]) << 48);
        *reinterpret_cast<unsigned long long*>(
            smem + wn * 128 + ((c * 2) ^ ((wn & 7) << 4))) = pk;
    }

    __syncthreads();   // the ONLY barrier; Ws read-only hereafter.

#define STOREA(SRC) {                                                         \
    _Pragma("unroll") for (int s = 0; s < 8; ++s) {                           \
        int rl = s * 2 + rl0;                                                 \
        *reinterpret_cast<unsigned long long*>(                               \
            Aslot + rl * 256 + ((u * 8) ^ ((rl & 7) << 4))) = pack4(SRC[s]); } }

#define BATCH(b_, CUR) {                                                      \
    STOREA(CUR);                                                              \
    if ((b_) < 2) LOADA(CUR, (b_) + 2);                                       \
    FENCE();   /* A-slot writes ordered+complete before fragment reads */     \
    _Pragma("unroll") for (int jj = 0; jj < 2; ++jj) {                        \
        bf16x8 af0 = *reinterpret_cast<const bf16x8*>(                        \
            Aslot + lr * 256 + ((jj * 128 + lk * 16) ^ ((lr & 7) << 4)));     \
        bf16x8 af1 = *reinterpret_cast<const bf16x8*>(                        \
            Aslot + lr * 256 + ((jj * 128 + 64 + lk * 16) ^ ((lr & 7) << 4)));\
        f32x4 acc[4];                                                         \
        _Pragma("unroll") for (int nt = 0; nt < 4; ++nt)                      \
            acc[nt] = (f32x4){0.f, 0.f, 0.f, 0.f};                            \
        _Pragma("unroll") for (int nt = 0; nt < 4; ++nt) {                    \
            int bn = jj * 64 + nt * 16 + lr;                                  \
            bf16x8 w0 = *reinterpret_cast<const bf16x8*>(                     \
                smem + bn * 128 + ((lk * 16) ^ ((bn & 7) << 4)));             \
            acc[nt] = __builtin_amdgcn_mfma_f32_16x16x32_bf16(                \
                af0, w0, acc[nt], 0, 0, 0);                                   \
        }                                                                     \
        _Pragma("unroll") for (int nt = 0; nt < 4; ++nt) {                    \
            int bn = jj * 64 + nt * 16 + lr;                                  \
            bf16x8 w1 = *reinterpret_cast<const bf16x8*>(                     \
                smem + bn * 128 + ((64 + lk * 16) ^ ((bn & 7) << 4)));        \
            acc[nt] = __builtin_amdgcn_mfma_f32_16x16x32_bf16(                \
                af1, w1, acc[nt], 0, 0, 0);                                   \
        }                                                                     \
        FENCE();   /* prior readback reads done before bounce overwrite */    \
        _Pragma("unroll") for (int nt = 0; nt < 4; ++nt)                      \
        _Pragma("unroll") for (int r = 0; r < 4; ++r) {                       \
            int brow = lk * 4 + r;                                            \
            *reinterpret_cast<float*>(                                        \
                Bslot + brow * 256 +                                          \
                (((nt * 16 + lr) * 4) ^ ((brow & 7) << 4))) = acc[nt][r];     \
        }                                                                     \
        FENCE();   /* bounce writes complete before readback */               \
        float* Ob = Obase + (size_t)(b_) * BSTRIDE + jj * 64;                 \
        _Pragma("unroll") for (int s2 = 0; s2 < 4; ++s2) {                    \
            int row = s2 * 4 + lk;                                            \
            int u2  = l & 15;                                                 \
            f32x4 v = *reinterpret_cast<const f32x4*>(                        \
                Bslot + row * 256 + ((u2 * 16) ^ ((row & 7) << 4)));          \
            __builtin_nontemporal_store(v,                                    \
                reinterpret_cast<f32x4*>(Ob + (size_t)row * 4096 + u2 * 4));  \
        }                                                                     \
    } }

    BATCH(0, aA);
    BATCH(1, aB);
    BATCH(2, aA);
    BATCH(3, aB);
}

extern "C" void kernel_launch(void* const* d_in, const int* in_sizes, int n_in,
                              void* d_out, int out_size, void* d_ws, size_t ws_size,
                              hipStream_t stream) {
    const float* x = (const float*)d_in[0];   // [4, 4096, 4096] fp32
    const float* w = (const float*)d_in[1];   // [4096, 4096] fp32
    float* out = (float*)d_out;               // [4, 4096, 4096] fp32

    dim3 grid(2048);
    dim3 block(256);
    block_matmul_kernel<<<grid, block, 0, stream>>>(x, w, out);
}